// Round 10
// baseline (334.615 us; speedup 1.0000x reference)
//
#include <hip/hip_runtime.h>
#include <hip/hip_bf16.h>

typedef __bf16 bf16x8 __attribute__((ext_vector_type(8)));
typedef float f32x4 __attribute__((ext_vector_type(4)));

#define BAR() __builtin_amdgcn_s_barrier()
#define MEMFENCE() asm volatile("" ::: "memory")
#define VMCNT8() asm volatile("s_waitcnt vmcnt(8)" ::: "memory")
#define VMCNT0() asm volatile("s_waitcnt vmcnt(0)" ::: "memory")

__device__ __forceinline__ void gload_lds16(const void* g, void* l) {
  __builtin_amdgcn_global_load_lds(
      (const __attribute__((address_space(1))) void*)g,
      (__attribute__((address_space(3))) void*)l, 16, 0, 0);
}

// ---------------- fused f32 -> bf16 convert (all 6 tensors) ----------------
// total = 15728640 elements; grid = 15728640/(256*4) = 15360 blocks
__global__ __launch_bounds__(256) void k_f2b_all(
    const float* __restrict__ x, const float* __restrict__ wk,
    const float* __restrict__ wq, const float* __restrict__ wv,
    const float* __restrict__ wi, const float* __restrict__ wo,
    __bf16* __restrict__ xb, __bf16* __restrict__ wqkv,
    __bf16* __restrict__ winb, __bf16* __restrict__ woutb) {
  int i = (blockIdx.x * 256 + threadIdx.x) * 4;
  const float* s; __bf16* d; int off;
  if (i < 4194304)       { s = x;  d = xb;             off = i; }
  else if (i < 5242880)  { s = wk; d = wqkv;           off = i - 4194304; }
  else if (i < 6291456)  { s = wq; d = wqkv + 1048576; off = i - 5242880; }
  else if (i < 7340032)  { s = wv; d = wqkv + 2097152; off = i - 6291456; }
  else if (i < 11534336) { s = wi; d = winb;           off = i - 7340032; }
  else                   { s = wo; d = woutb;          off = i - 11534336; }
  const float4 v = *(const float4*)(s + off);
  d[off + 0] = (__bf16)v.x;
  d[off + 1] = (__bf16)v.y;
  d[off + 2] = (__bf16)v.z;
  d[off + 3] = (__bf16)v.w;
}

// ---------------- NT GEMM v2: counted-vmcnt double-buffered pipeline -------
template <int EPI, int WM, int WN, int MI, int NI>
__global__ __launch_bounds__(WM * WN * 64, 2) void k_gemm(
    const __bf16* __restrict__ A, const __bf16* __restrict__ B, int N, int K,
    int NT, const float* __restrict__ bias, const float* __restrict__ resid,
    float* __restrict__ outf, __bf16* __restrict__ outb,
    __bf16* __restrict__ ok, __bf16* __restrict__ oq, __bf16* __restrict__ ovt) {
  constexpr int BM = WM * MI * 16, BN = WN * NI * 16;
  constexpr int LA = BM / (8 * WM * WN);
  constexpr int LB = BN / (8 * WM * WN);
  __shared__ __align__(16) __bf16 lds[2][(BM + BN) * 64];
  const int tid = threadIdx.x;
  const int lane = tid & 63, wid = tid >> 6;
  const int wr = wid / WN, wc = wid % WN;
  const int lr = lane & 15, lh = lane >> 4;
  const int bid = blockIdx.x;
  const int cpx = gridDim.x >> 3;
  const int sid = (bid & 7) * cpx + (bid >> 3);
  const int mt = sid / NT, nt = sid - mt * NT;
  const int m0 = mt * BM, n0 = nt * BN;
  const int nkt = K >> 6;

  auto stage = [&](int t, int bufi) {
    const int k0 = t << 6;
    __bf16* As = lds[bufi];
    __bf16* Bs = lds[bufi] + BM * 64;
#pragma unroll
    for (int j = 0; j < LA; ++j) {
      int chunk = (wid * LA + j) * 64 + lane;
      int row = chunk >> 3, c8 = chunk & 7;
      int g8 = c8 ^ (row & 7);
      gload_lds16(A + (size_t)(m0 + row) * K + k0 + g8 * 8, As + chunk * 8);
    }
#pragma unroll
    for (int j = 0; j < LB; ++j) {
      int chunk = (wid * LB + j) * 64 + lane;
      int row = chunk >> 3, c8 = chunk & 7;
      int g8 = c8 ^ (row & 7);
      gload_lds16(B + (size_t)(n0 + row) * K + k0 + g8 * 8, Bs + chunk * 8);
    }
  };

  f32x4 acc[MI][NI] = {};
  stage(0, 0);
  stage(1, 1);
  VMCNT8();
  BAR();

  for (int t = 0; t < nkt; ++t) {
    const __bf16* As = lds[t & 1];
    const __bf16* Bs = lds[t & 1] + BM * 64;
#pragma unroll
    for (int ks = 0; ks < 2; ++ks) {
      bf16x8 af[MI], bf[NI];
#pragma unroll
      for (int mi = 0; mi < MI; ++mi) {
        int row = wr * (MI * 16) + mi * 16 + lr;
        af[mi] = *(const bf16x8*)&As[row * 64 + (((ks * 4 + lh) ^ (row & 7)) * 8)];
      }
#pragma unroll
      for (int ni = 0; ni < NI; ++ni) {
        int row = wc * (NI * 16) + ni * 16 + lr;
        bf[ni] = *(const bf16x8*)&Bs[row * 64 + (((ks * 4 + lh) ^ (row & 7)) * 8)];
      }
#pragma unroll
      for (int mi = 0; mi < MI; ++mi)
#pragma unroll
        for (int ni = 0; ni < NI; ++ni)
          acc[mi][ni] = __builtin_amdgcn_mfma_f32_16x16x32_bf16(
              af[mi], bf[ni], acc[mi][ni], 0, 0, 0);
    }
    MEMFENCE();
    BAR();
    if (t + 2 < nkt) {
      stage(t + 2, t & 1);
      VMCNT8();
    } else {
      VMCNT0();
    }
    BAR();
  }

#pragma unroll
  for (int mi = 0; mi < MI; ++mi) {
#pragma unroll
    for (int j = 0; j < 4; ++j) {
      const int row = m0 + wr * (MI * 16) + mi * 16 + lh * 4 + j;
#pragma unroll
      for (int ni = 0; ni < NI; ++ni) {
        const int col = n0 + wc * (NI * 16) + ni * 16 + lr;
        float v = acc[mi][ni][j];
        if constexpr (EPI == 0) {
          const int which = col >> 10, c = col & 1023;
          const int ih = c >> 6, hh = c & 63;
          const int bb = row >> 11, pp = row & 2047;
          const int bi = bb * 16 + ih;
          if (which == 0)
            ok[((size_t)bi * 2048 + pp) * 64 + hh] = (__bf16)v;
          else if (which == 1)
            oq[((size_t)bi * 2048 + pp) * 64 + hh] = (__bf16)v;
          else
            ovt[((size_t)bi * 64 + hh) * 2048 + pp] = (__bf16)v;
        } else if constexpr (EPI == 1) {
          float h = v + bias[col];
          float g = 0.5f * h * (1.f + erff(h * 0.70710678118f));
          outb[(size_t)row * N + col] = (__bf16)g;
        } else {
          outf[(size_t)row * N + col] = v + bias[col] + resid[(size_t)row * N + col];
        }
      }
    }
  }
}

// ---------------- flash attention v6: 2-wave split-K (causal, UNSCALED) -----
// No max tracking -> partial (o, lsum) are PURELY ADDITIVE across kv ranges.
// Block = 128 threads = 2 waves; wave w handles kv-tiles [w*half, ...).
// Same L2 traffic as QBLK=32 (each kv tile read once per block), but 4096
// waves total = 16 waves/CU ceiling (vs 8 before). v4 low-VGPR inner loop.
__global__ __launch_bounds__(128, 4) void k_attn(const __bf16* __restrict__ kb,
                                                 const __bf16* __restrict__ qb,
                                                 const __bf16* __restrict__ vt,
                                                 float* __restrict__ z) {
  const int tid = threadIdx.x;
  const int lane = tid & 63, w = tid >> 6;
  const int lr = lane & 15, lh = lane >> 4;
  const int wgid = blockIdx.x;
  const int xcd = wgid & 7;
  const int t = wgid >> 3;            // 0..255
  const int bi = xcd + 8 * (t & 3);   // bi % 8 == xcd; 4 bi per XCD
  const int qt = 63 - (t >> 2);       // biggest causal tiles first
  const int b = bi >> 4, ih = bi & 15;
  const int q0 = qt * 32;
  const __bf16* kbase = kb + (size_t)bi * 2048 * 64;
  const __bf16* qbase = qb + (size_t)bi * 2048 * 64;
  const __bf16* vbase = vt + (size_t)bi * 64 * 2048;

  bf16x8 aq[2][2];
#pragma unroll
  for (int tl = 0; tl < 2; ++tl)
#pragma unroll
    for (int ks = 0; ks < 2; ++ks)
      aq[tl][ks] = *(const bf16x8*)(qbase + (size_t)(q0 + tl * 16 + lr) * 64 + ks * 32 + lh * 8);

  f32x4 o[2][4] = {};
  float lsum[2][4] = {};

  __shared__ __align__(16) __bf16 plds[2][2][16 * 72];  // [wave][tl]
  __shared__ __align__(16) float cmb_o[2][4][64][4];    // [tl][ht][lane][j] 8KB
  __shared__ float cmb_l[2][4][64];                     // [tl][j][lane] 2KB

  const int nk = (q0 + 32 + 63) >> 6;
  const int half0 = (nk + 1) >> 1;
  const int kbeg = w ? half0 : 0;
  const int kend = w ? nk : half0;

  if (kbeg < kend) {
    // preload first K tile of this wave's range
    bf16x8 bk[4][2];
#pragma unroll
    for (int n = 0; n < 4; ++n)
#pragma unroll
      for (int ks = 0; ks < 2; ++ks)
        bk[n][ks] = *(const bf16x8*)(kbase + (size_t)(kbeg * 64 + n * 16 + lr) * 64 + ks * 32 + lh * 8);

    for (int kt = kbeg; kt < kend; ++kt) {
      const int k0 = kt * 64;
      bf16x8 bv[4][2];
#pragma unroll
      for (int ht = 0; ht < 4; ++ht)
#pragma unroll
        for (int ks = 0; ks < 2; ++ks)
          bv[ht][ks] = *(const bf16x8*)(vbase + (size_t)(ht * 16 + lr) * 2048 + k0 + ks * 32 + lh * 8);

      f32x4 s[2][4] = {};
#pragma unroll
      for (int ks = 0; ks < 2; ++ks)
#pragma unroll
        for (int n = 0; n < 4; ++n) {
          s[0][n] = __builtin_amdgcn_mfma_f32_16x16x32_bf16(aq[0][ks], bk[n][ks], s[0][n], 0, 0, 0);
          s[1][n] = __builtin_amdgcn_mfma_f32_16x16x32_bf16(aq[1][ks], bk[n][ks], s[1][n], 0, 0, 0);
        }

      if (kt + 1 < kend) {
#pragma unroll
        for (int n = 0; n < 4; ++n)
#pragma unroll
          for (int ks = 0; ks < 2; ++ks)
            bk[n][ks] = *(const bf16x8*)(kbase + (size_t)(k0 + 64 + n * 16 + lr) * 64 + ks * 32 + lh * 8);
      }

      if (kt == nk - 1) {  // only the globally-last tile straddles the diagonal
#pragma unroll
        for (int tl = 0; tl < 2; ++tl)
#pragma unroll
          for (int n = 0; n < 4; ++n)
#pragma unroll
            for (int j = 0; j < 4; ++j) {
              int qpos = q0 + tl * 16 + lh * 4 + j;
              int kpos = k0 + n * 16 + lr;
              if (kpos > qpos) s[tl][n][j] = -1e10f;
            }
      }

      float p[2][4][4];
#pragma unroll
      for (int tl = 0; tl < 2; ++tl) {
#pragma unroll
        for (int n = 0; n < 4; ++n)
#pragma unroll
          for (int j = 0; j < 4; ++j) p[tl][n][j] = __expf(s[tl][n][j]);
#pragma unroll
        for (int j = 0; j < 4; ++j)
          lsum[tl][j] += (p[tl][0][j] + p[tl][1][j]) + (p[tl][2][j] + p[tl][3][j]);
      }

      // P transpose through wave-private LDS (intra-wave lgkmcnt ordering)
#pragma unroll
      for (int tl = 0; tl < 2; ++tl)
#pragma unroll
        for (int n = 0; n < 4; ++n)
#pragma unroll
          for (int j = 0; j < 4; ++j)
            plds[w][tl][(lh * 4 + j) * 72 + n * 16 + lr] = (__bf16)p[tl][n][j];
      bf16x8 pa[2][2];
#pragma unroll
      for (int tl = 0; tl < 2; ++tl)
#pragma unroll
        for (int ks = 0; ks < 2; ++ks)
          pa[tl][ks] = *(const bf16x8*)&plds[w][tl][lr * 72 + ks * 32 + lh * 8];
#pragma unroll
      for (int ks = 0; ks < 2; ++ks)
#pragma unroll
        for (int ht = 0; ht < 4; ++ht) {
          o[0][ht] = __builtin_amdgcn_mfma_f32_16x16x32_bf16(pa[0][ks], bv[ht][ks], o[0][ht], 0, 0, 0);
          o[1][ht] = __builtin_amdgcn_mfma_f32_16x16x32_bf16(pa[1][ks], bv[ht][ks], o[1][ht], 0, 0, 0);
        }
    }
  }

  // wave-local cross-lane reduce of lsum (over the 16 lr lanes)
#pragma unroll
  for (int m = 1; m < 16; m <<= 1)
#pragma unroll
    for (int tl = 0; tl < 2; ++tl)
#pragma unroll
      for (int j = 0; j < 4; ++j) lsum[tl][j] += __shfl_xor(lsum[tl][j], m);

  // combine: wave1 publishes partials; wave0 adds, normalizes, writes
  if (w == 1) {
#pragma unroll
    for (int tl = 0; tl < 2; ++tl) {
#pragma unroll
      for (int ht = 0; ht < 4; ++ht)
        *(f32x4*)&cmb_o[tl][ht][lane][0] = o[tl][ht];
#pragma unroll
      for (int j = 0; j < 4; ++j) cmb_l[tl][j][lane] = lsum[tl][j];
    }
  }
  __syncthreads();
  if (w == 0) {
    float* zr = z + (size_t)b * 2048 * 1024;
#pragma unroll
    for (int tl = 0; tl < 2; ++tl)
#pragma unroll
      for (int j = 0; j < 4; ++j) {
        float lt = lsum[tl][j] + cmb_l[tl][j][lane];
        float inv = 1.f / lt;
        int q = q0 + tl * 16 + lh * 4 + j;
#pragma unroll
        for (int ht = 0; ht < 4; ++ht) {
          f32x4 ov = o[tl][ht];
          f32x4 ow = *(const f32x4*)&cmb_o[tl][ht][lane][0];
          zr[(size_t)q * 1024 + ih * 64 + ht * 16 + lr] = (ov[j] + ow[j]) * inv;
        }
      }
  }
}

// ---------------- residual + custom LayerNorm ----------------
__global__ __launch_bounds__(256) void k_ln(const float* __restrict__ x,
                                            const float* __restrict__ z,
                                            const float* __restrict__ wln,
                                            const float* __restrict__ bln,
                                            float* __restrict__ y,
                                            __bf16* __restrict__ yb) {
  const int row = blockIdx.x;
  const int t = threadIdx.x;
  const int lane = t & 63, wid = t >> 6;
  const float4 xv = ((const float4*)(x + (size_t)row * 1024))[t];
  const float4 zv = ((const float4*)(z + (size_t)row * 1024))[t];
  float v0 = xv.x + zv.x, v1 = xv.y + zv.y, v2 = xv.z + zv.z, v3 = xv.w + zv.w;
  __shared__ float red[4];
  float s = v0 + v1 + v2 + v3;
#pragma unroll
  for (int m = 1; m < 64; m <<= 1) s += __shfl_xor(s, m);
  if (lane == 0) red[wid] = s;
  __syncthreads();
  const float mean = (red[0] + red[1] + red[2] + red[3]) * (1.f / 1024.f);
  const float c0 = v0 - mean, c1 = v1 - mean, c2 = v2 - mean, c3 = v3 - mean;
  float ss = c0 * c0 + c1 * c1 + c2 * c2 + c3 * c3;
#pragma unroll
  for (int m = 1; m < 64; m <<= 1) ss += __shfl_xor(ss, m);
  __syncthreads();
  if (lane == 0) red[wid] = ss;
  __syncthreads();
  const float var = (red[0] + red[1] + red[2] + red[3]) * (1.f / 1023.f);
  const float inv = 1.f / (sqrtf(var) + 1e-4f);
  const float4 wv = ((const float4*)wln)[t];
  const float4 bv = ((const float4*)bln)[t];
  float y0 = c0 * inv * wv.x + bv.x;
  float y1 = c1 * inv * wv.y + bv.y;
  float y2 = c2 * inv * wv.z + bv.z;
  float y3 = c3 * inv * wv.w + bv.w;
  float4 yo; yo.x = y0; yo.y = y1; yo.z = y2; yo.w = y3;
  ((float4*)(y + (size_t)row * 1024))[t] = yo;
  __bf16* yd = yb + (size_t)row * 1024 + t * 4;
  yd[0] = (__bf16)y0; yd[1] = (__bf16)y1; yd[2] = (__bf16)y2; yd[3] = (__bf16)y3;
}

// ---------------- launch ----------------
extern "C" void kernel_launch(void* const* d_in, const int* in_sizes, int n_in,
                              void* d_out, int out_size, void* d_ws, size_t ws_size,
                              hipStream_t stream) {
  const float* x = (const float*)d_in[0];
  const float* W_K = (const float*)d_in[1];
  const float* W_Q = (const float*)d_in[2];
  const float* W_V = (const float*)d_in[3];
  const float* w_ln = (const float*)d_in[4];
  const float* b_ln = (const float*)d_in[5];
  const float* W_in = (const float*)d_in[6];
  const float* b_in = (const float*)d_in[7];
  const float* W_out = (const float*)d_in[8];
  const float* b_out = (const float*)d_in[9];
  float* out = (float*)d_out;

  char* ws = (char*)d_ws;
  const size_t NEEDED = 132120576;  // ~126 MB
  if (ws_size < NEEDED) return;

  __bf16* xb   = (__bf16*)(ws);                //  8 MB  [4096,1024]
  __bf16* wqkv = (__bf16*)(ws + 8388608);      //  6 MB  [3072,1024] K,Q,V stacked
  __bf16* winb = (__bf16*)(ws + 14680064);     //  8 MB  [4096,1024]
  __bf16* woutb= (__bf16*)(ws + 23068672);     //  8 MB  [1024,4096]
  __bf16* kbuf = (__bf16*)(ws + 31457280);     //  8 MB  [b,i,p,h]
  __bf16* qbuf = (__bf16*)(ws + 39845888);     //  8 MB  [b,i,p,h]
  __bf16* vtb  = (__bf16*)(ws + 48234496);     //  8 MB  [b,i,h,p]
  float*  zb   = (float*)(ws + 56623104);      // 16 MB  [b,p,1024]
  float*  yf   = (float*)(ws + 73400320);      // 16 MB  LN out f32
  __bf16* ybb  = (__bf16*)(ws + 90177536);     //  8 MB  LN out bf16
  __bf16* hact = (__bf16*)(ws + 98566144);     // 32 MB  [4096,4096]

  // fused f32->bf16: 15,728,640 elements / 4 per thread / 256 = 15360 blocks
  k_f2b_all<<<15360, 256, 0, stream>>>(x, W_K, W_Q, W_V, W_in, W_out,
                                       xb, wqkv, winb, woutb);

  // QKV projection: [4096,1024] x [3072,1024]^T  (256x256 tiles, 192 blocks)
  k_gemm<0, 2, 4, 8, 4><<<192, 512, 0, stream>>>(xb, wqkv, 3072, 1024, 12,
                                                 nullptr, nullptr, nullptr,
                                                 nullptr, kbuf, qbuf, vtb);
  // attention: 2048 blocks x 2 waves (split-K), bi->XCD affinity swizzle
  k_attn<<<dim3(2048), 128, 0, stream>>>(kbuf, qbuf, vtb, zb);
  // residual + LN
  k_ln<<<4096, 256, 0, stream>>>(x, zb, w_ln, b_ln, yf, ybb);
  // MLP in + GELU: [4096,1024] x [4096,1024]^T  (256x256 tiles, 256 blocks)
  k_gemm<1, 2, 4, 8, 4><<<256, 512, 0, stream>>>(ybb, winb, 4096, 1024, 16,
                                                 b_in, nullptr, nullptr, hact,
                                                 nullptr, nullptr, nullptr);
  // MLP out + bias + residual: [4096,4096] x [1024,4096]^T (128x128, 256 blocks)
  k_gemm<2, 2, 2, 4, 4><<<256, 256, 0, stream>>>(hact, woutb, 1024, 4096, 8,
                                                 b_out, yf, out, nullptr,
                                                 nullptr, nullptr, nullptr);
}

// Round 11
// 248.016 us; speedup vs baseline: 1.3492x; 1.3492x over previous
//
#include <hip/hip_runtime.h>
#include <hip/hip_bf16.h>

typedef __bf16 bf16x8 __attribute__((ext_vector_type(8)));
typedef float f32x4 __attribute__((ext_vector_type(4)));

#define BAR() __builtin_amdgcn_s_barrier()
#define MEMFENCE() asm volatile("" ::: "memory")
#define VMCNT8() asm volatile("s_waitcnt vmcnt(8)" ::: "memory")
#define VMCNT0() asm volatile("s_waitcnt vmcnt(0)" ::: "memory")

__device__ __forceinline__ void gload_lds16(const void* g, void* l) {
  __builtin_amdgcn_global_load_lds(
      (const __attribute__((address_space(1))) void*)g,
      (__attribute__((address_space(3))) void*)l, 16, 0, 0);
}

// ---------------- fused f32 -> bf16 convert (all 6 tensors) ----------------
// total = 15728640 elements; grid = 15728640/(256*4) = 15360 blocks
__global__ __launch_bounds__(256) void k_f2b_all(
    const float* __restrict__ x, const float* __restrict__ wk,
    const float* __restrict__ wq, const float* __restrict__ wv,
    const float* __restrict__ wi, const float* __restrict__ wo,
    __bf16* __restrict__ xb, __bf16* __restrict__ wqkv,
    __bf16* __restrict__ winb, __bf16* __restrict__ woutb) {
  int i = (blockIdx.x * 256 + threadIdx.x) * 4;
  const float* s; __bf16* d; int off;
  if (i < 4194304)       { s = x;  d = xb;             off = i; }
  else if (i < 5242880)  { s = wk; d = wqkv;           off = i - 4194304; }
  else if (i < 6291456)  { s = wq; d = wqkv + 1048576; off = i - 5242880; }
  else if (i < 7340032)  { s = wv; d = wqkv + 2097152; off = i - 6291456; }
  else if (i < 11534336) { s = wi; d = winb;           off = i - 7340032; }
  else                   { s = wo; d = woutb;          off = i - 11534336; }
  const float4 v = *(const float4*)(s + off);
  d[off + 0] = (__bf16)v.x;
  d[off + 1] = (__bf16)v.y;
  d[off + 2] = (__bf16)v.z;
  d[off + 3] = (__bf16)v.w;
}

// ---------------- NT GEMM v2: counted-vmcnt double-buffered pipeline -------
template <int EPI, int WM, int WN, int MI, int NI>
__global__ __launch_bounds__(WM * WN * 64, 2) void k_gemm(
    const __bf16* __restrict__ A, const __bf16* __restrict__ B, int N, int K,
    int NT, const float* __restrict__ bias, const float* __restrict__ resid,
    float* __restrict__ outf, __bf16* __restrict__ outb,
    __bf16* __restrict__ ok, __bf16* __restrict__ oq, __bf16* __restrict__ ovt) {
  constexpr int BM = WM * MI * 16, BN = WN * NI * 16;
  constexpr int LA = BM / (8 * WM * WN);
  constexpr int LB = BN / (8 * WM * WN);
  __shared__ __align__(16) __bf16 lds[2][(BM + BN) * 64];
  const int tid = threadIdx.x;
  const int lane = tid & 63, wid = tid >> 6;
  const int wr = wid / WN, wc = wid % WN;
  const int lr = lane & 15, lh = lane >> 4;
  const int bid = blockIdx.x;
  const int cpx = gridDim.x >> 3;
  const int sid = (bid & 7) * cpx + (bid >> 3);
  const int mt = sid / NT, nt = sid - mt * NT;
  const int m0 = mt * BM, n0 = nt * BN;
  const int nkt = K >> 6;

  auto stage = [&](int t, int bufi) {
    const int k0 = t << 6;
    __bf16* As = lds[bufi];
    __bf16* Bs = lds[bufi] + BM * 64;
#pragma unroll
    for (int j = 0; j < LA; ++j) {
      int chunk = (wid * LA + j) * 64 + lane;
      int row = chunk >> 3, c8 = chunk & 7;
      int g8 = c8 ^ (row & 7);
      gload_lds16(A + (size_t)(m0 + row) * K + k0 + g8 * 8, As + chunk * 8);
    }
#pragma unroll
    for (int j = 0; j < LB; ++j) {
      int chunk = (wid * LB + j) * 64 + lane;
      int row = chunk >> 3, c8 = chunk & 7;
      int g8 = c8 ^ (row & 7);
      gload_lds16(B + (size_t)(n0 + row) * K + k0 + g8 * 8, Bs + chunk * 8);
    }
  };

  f32x4 acc[MI][NI] = {};
  stage(0, 0);
  stage(1, 1);
  VMCNT8();
  BAR();

  for (int t = 0; t < nkt; ++t) {
    const __bf16* As = lds[t & 1];
    const __bf16* Bs = lds[t & 1] + BM * 64;
#pragma unroll
    for (int ks = 0; ks < 2; ++ks) {
      bf16x8 af[MI], bf[NI];
#pragma unroll
      for (int mi = 0; mi < MI; ++mi) {
        int row = wr * (MI * 16) + mi * 16 + lr;
        af[mi] = *(const bf16x8*)&As[row * 64 + (((ks * 4 + lh) ^ (row & 7)) * 8)];
      }
#pragma unroll
      for (int ni = 0; ni < NI; ++ni) {
        int row = wc * (NI * 16) + ni * 16 + lr;
        bf[ni] = *(const bf16x8*)&Bs[row * 64 + (((ks * 4 + lh) ^ (row & 7)) * 8)];
      }
#pragma unroll
      for (int mi = 0; mi < MI; ++mi)
#pragma unroll
        for (int ni = 0; ni < NI; ++ni)
          acc[mi][ni] = __builtin_amdgcn_mfma_f32_16x16x32_bf16(
              af[mi], bf[ni], acc[mi][ni], 0, 0, 0);
    }
    MEMFENCE();
    BAR();
    if (t + 2 < nkt) {
      stage(t + 2, t & 1);
      VMCNT8();
    } else {
      VMCNT0();
    }
    BAR();
  }

#pragma unroll
  for (int mi = 0; mi < MI; ++mi) {
#pragma unroll
    for (int j = 0; j < 4; ++j) {
      const int row = m0 + wr * (MI * 16) + mi * 16 + lh * 4 + j;
#pragma unroll
      for (int ni = 0; ni < NI; ++ni) {
        const int col = n0 + wc * (NI * 16) + ni * 16 + lr;
        float v = acc[mi][ni][j];
        if constexpr (EPI == 0) {
          const int which = col >> 10, c = col & 1023;
          const int ih = c >> 6, hh = c & 63;
          const int bb = row >> 11, pp = row & 2047;
          const int bi = bb * 16 + ih;
          if (which == 0)
            ok[((size_t)bi * 2048 + pp) * 64 + hh] = (__bf16)v;
          else if (which == 1)
            oq[((size_t)bi * 2048 + pp) * 64 + hh] = (__bf16)v;
          else
            ovt[((size_t)bi * 64 + hh) * 2048 + pp] = (__bf16)v;
        } else if constexpr (EPI == 1) {
          float h = v + bias[col];
          float g = 0.5f * h * (1.f + erff(h * 0.70710678118f));
          outb[(size_t)row * N + col] = (__bf16)g;
        } else {
          outf[(size_t)row * N + col] = v + bias[col] + resid[(size_t)row * N + col];
        }
      }
    }
  }
}

// ---------------- flash attention v6b: 2-wave split-K (causal, UNSCALED) ----
// v6 regression root-cause: __launch_bounds__(128,4) forced VGPR->64 and the
// whole working set spilled to scratch (WRITE_SIZE 346MB). v6b: no min-waves
// hint (allocator picks ~140-170), exp computed IN PLACE in s (saves 32 regs).
// Split-K: wave w handles kv-tiles [w*half..); partial (o,lsum) are purely
// additive (no max tracking); one LDS combine at the end.
__global__ __launch_bounds__(128) void k_attn(const __bf16* __restrict__ kb,
                                              const __bf16* __restrict__ qb,
                                              const __bf16* __restrict__ vt,
                                              float* __restrict__ z) {
  const int tid = threadIdx.x;
  const int lane = tid & 63, w = tid >> 6;
  const int lr = lane & 15, lh = lane >> 4;
  const int wgid = blockIdx.x;
  const int xcd = wgid & 7;
  const int t = wgid >> 3;            // 0..255
  const int bi = xcd + 8 * (t & 3);   // bi % 8 == xcd; 4 bi per XCD
  const int qt = 63 - (t >> 2);       // biggest causal tiles first
  const int b = bi >> 4, ih = bi & 15;
  const int q0 = qt * 32;
  const __bf16* kbase = kb + (size_t)bi * 2048 * 64;
  const __bf16* qbase = qb + (size_t)bi * 2048 * 64;
  const __bf16* vbase = vt + (size_t)bi * 64 * 2048;

  bf16x8 aq[2][2];
#pragma unroll
  for (int tl = 0; tl < 2; ++tl)
#pragma unroll
    for (int ks = 0; ks < 2; ++ks)
      aq[tl][ks] = *(const bf16x8*)(qbase + (size_t)(q0 + tl * 16 + lr) * 64 + ks * 32 + lh * 8);

  f32x4 o[2][4] = {};
  float lsum[2][4] = {};

  __shared__ __align__(16) __bf16 plds[2][2][16 * 72];  // [wave][tl]
  __shared__ __align__(16) float cmb_o[2][4][64][4];    // [tl][ht][lane][j] 8KB
  __shared__ float cmb_l[2][4][64];                     // [tl][j][lane] 2KB

  const int nk = (q0 + 32 + 63) >> 6;
  const int half0 = (nk + 1) >> 1;
  const int kbeg = w ? half0 : 0;
  const int kend = w ? nk : half0;

  if (kbeg < kend) {
    bf16x8 bk[4][2];
#pragma unroll
    for (int n = 0; n < 4; ++n)
#pragma unroll
      for (int ks = 0; ks < 2; ++ks)
        bk[n][ks] = *(const bf16x8*)(kbase + (size_t)(kbeg * 64 + n * 16 + lr) * 64 + ks * 32 + lh * 8);

    for (int kt = kbeg; kt < kend; ++kt) {
      const int k0 = kt * 64;
      bf16x8 bv[4][2];
#pragma unroll
      for (int ht = 0; ht < 4; ++ht)
#pragma unroll
        for (int ks = 0; ks < 2; ++ks)
          bv[ht][ks] = *(const bf16x8*)(vbase + (size_t)(ht * 16 + lr) * 2048 + k0 + ks * 32 + lh * 8);

      f32x4 s[2][4] = {};
#pragma unroll
      for (int ks = 0; ks < 2; ++ks)
#pragma unroll
        for (int n = 0; n < 4; ++n) {
          s[0][n] = __builtin_amdgcn_mfma_f32_16x16x32_bf16(aq[0][ks], bk[n][ks], s[0][n], 0, 0, 0);
          s[1][n] = __builtin_amdgcn_mfma_f32_16x16x32_bf16(aq[1][ks], bk[n][ks], s[1][n], 0, 0, 0);
        }

      if (kt + 1 < kend) {
#pragma unroll
        for (int n = 0; n < 4; ++n)
#pragma unroll
          for (int ks = 0; ks < 2; ++ks)
            bk[n][ks] = *(const bf16x8*)(kbase + (size_t)(k0 + 64 + n * 16 + lr) * 64 + ks * 32 + lh * 8);
      }

      if (kt == nk - 1) {  // only the globally-last tile straddles the diagonal
#pragma unroll
        for (int tl = 0; tl < 2; ++tl)
#pragma unroll
          for (int n = 0; n < 4; ++n)
#pragma unroll
            for (int j = 0; j < 4; ++j) {
              int qpos = q0 + tl * 16 + lh * 4 + j;
              int kpos = k0 + n * 16 + lr;
              if (kpos > qpos) s[tl][n][j] = -1e10f;
            }
      }

      // exp IN PLACE (saves 32 VGPRs vs separate p[][][])
#pragma unroll
      for (int tl = 0; tl < 2; ++tl) {
#pragma unroll
        for (int n = 0; n < 4; ++n)
#pragma unroll
          for (int j = 0; j < 4; ++j) s[tl][n][j] = __expf(s[tl][n][j]);
#pragma unroll
        for (int j = 0; j < 4; ++j)
          lsum[tl][j] += (s[tl][0][j] + s[tl][1][j]) + (s[tl][2][j] + s[tl][3][j]);
      }

      // P transpose through wave-private LDS (intra-wave lgkmcnt ordering)
#pragma unroll
      for (int tl = 0; tl < 2; ++tl)
#pragma unroll
        for (int n = 0; n < 4; ++n)
#pragma unroll
          for (int j = 0; j < 4; ++j)
            plds[w][tl][(lh * 4 + j) * 72 + n * 16 + lr] = (__bf16)s[tl][n][j];
      bf16x8 pa[2][2];
#pragma unroll
      for (int tl = 0; tl < 2; ++tl)
#pragma unroll
        for (int ks = 0; ks < 2; ++ks)
          pa[tl][ks] = *(const bf16x8*)&plds[w][tl][lr * 72 + ks * 32 + lh * 8];
#pragma unroll
      for (int ks = 0; ks < 2; ++ks)
#pragma unroll
        for (int ht = 0; ht < 4; ++ht) {
          o[0][ht] = __builtin_amdgcn_mfma_f32_16x16x32_bf16(pa[0][ks], bv[ht][ks], o[0][ht], 0, 0, 0);
          o[1][ht] = __builtin_amdgcn_mfma_f32_16x16x32_bf16(pa[1][ks], bv[ht][ks], o[1][ht], 0, 0, 0);
        }
    }
  }

  // wave-local cross-lane reduce of lsum (over the 16 lr lanes)
#pragma unroll
  for (int m = 1; m < 16; m <<= 1)
#pragma unroll
    for (int tl = 0; tl < 2; ++tl)
#pragma unroll
      for (int j = 0; j < 4; ++j) lsum[tl][j] += __shfl_xor(lsum[tl][j], m);

  // combine: wave1 publishes partials; wave0 adds, normalizes, writes
  if (w == 1) {
#pragma unroll
    for (int tl = 0; tl < 2; ++tl) {
#pragma unroll
      for (int ht = 0; ht < 4; ++ht)
        *(f32x4*)&cmb_o[tl][ht][lane][0] = o[tl][ht];
#pragma unroll
      for (int j = 0; j < 4; ++j) cmb_l[tl][j][lane] = lsum[tl][j];
    }
  }
  __syncthreads();
  if (w == 0) {
    float* zr = z + (size_t)b * 2048 * 1024;
#pragma unroll
    for (int tl = 0; tl < 2; ++tl)
#pragma unroll
      for (int j = 0; j < 4; ++j) {
        float lt = lsum[tl][j] + cmb_l[tl][j][lane];
        float inv = 1.f / lt;
        int q = q0 + tl * 16 + lh * 4 + j;
#pragma unroll
        for (int ht = 0; ht < 4; ++ht) {
          f32x4 ov = o[tl][ht];
          f32x4 ow = *(const f32x4*)&cmb_o[tl][ht][lane][0];
          zr[(size_t)q * 1024 + ih * 64 + ht * 16 + lr] = (ov[j] + ow[j]) * inv;
        }
      }
  }
}

// ---------------- residual + custom LayerNorm ----------------
__global__ __launch_bounds__(256) void k_ln(const float* __restrict__ x,
                                            const float* __restrict__ z,
                                            const float* __restrict__ wln,
                                            const float* __restrict__ bln,
                                            float* __restrict__ y,
                                            __bf16* __restrict__ yb) {
  const int row = blockIdx.x;
  const int t = threadIdx.x;
  const int lane = t & 63, wid = t >> 6;
  const float4 xv = ((const float4*)(x + (size_t)row * 1024))[t];
  const float4 zv = ((const float4*)(z + (size_t)row * 1024))[t];
  float v0 = xv.x + zv.x, v1 = xv.y + zv.y, v2 = xv.z + zv.z, v3 = xv.w + zv.w;
  __shared__ float red[4];
  float s = v0 + v1 + v2 + v3;
#pragma unroll
  for (int m = 1; m < 64; m <<= 1) s += __shfl_xor(s, m);
  if (lane == 0) red[wid] = s;
  __syncthreads();
  const float mean = (red[0] + red[1] + red[2] + red[3]) * (1.f / 1024.f);
  const float c0 = v0 - mean, c1 = v1 - mean, c2 = v2 - mean, c3 = v3 - mean;
  float ss = c0 * c0 + c1 * c1 + c2 * c2 + c3 * c3;
#pragma unroll
  for (int m = 1; m < 64; m <<= 1) ss += __shfl_xor(ss, m);
  __syncthreads();
  if (lane == 0) red[wid] = ss;
  __syncthreads();
  const float var = (red[0] + red[1] + red[2] + red[3]) * (1.f / 1023.f);
  const float inv = 1.f / (sqrtf(var) + 1e-4f);
  const float4 wv = ((const float4*)wln)[t];
  const float4 bv = ((const float4*)bln)[t];
  float y0 = c0 * inv * wv.x + bv.x;
  float y1 = c1 * inv * wv.y + bv.y;
  float y2 = c2 * inv * wv.z + bv.z;
  float y3 = c3 * inv * wv.w + bv.w;
  float4 yo; yo.x = y0; yo.y = y1; yo.z = y2; yo.w = y3;
  ((float4*)(y + (size_t)row * 1024))[t] = yo;
  __bf16* yd = yb + (size_t)row * 1024 + t * 4;
  yd[0] = (__bf16)y0; yd[1] = (__bf16)y1; yd[2] = (__bf16)y2; yd[3] = (__bf16)y3;
}

// ---------------- launch ----------------
extern "C" void kernel_launch(void* const* d_in, const int* in_sizes, int n_in,
                              void* d_out, int out_size, void* d_ws, size_t ws_size,
                              hipStream_t stream) {
  const float* x = (const float*)d_in[0];
  const float* W_K = (const float*)d_in[1];
  const float* W_Q = (const float*)d_in[2];
  const float* W_V = (const float*)d_in[3];
  const float* w_ln = (const float*)d_in[4];
  const float* b_ln = (const float*)d_in[5];
  const float* W_in = (const float*)d_in[6];
  const float* b_in = (const float*)d_in[7];
  const float* W_out = (const float*)d_in[8];
  const float* b_out = (const float*)d_in[9];
  float* out = (float*)d_out;

  char* ws = (char*)d_ws;
  const size_t NEEDED = 132120576;  // ~126 MB
  if (ws_size < NEEDED) return;

  __bf16* xb   = (__bf16*)(ws);                //  8 MB  [4096,1024]
  __bf16* wqkv = (__bf16*)(ws + 8388608);      //  6 MB  [3072,1024] K,Q,V stacked
  __bf16* winb = (__bf16*)(ws + 14680064);     //  8 MB  [4096,1024]
  __bf16* woutb= (__bf16*)(ws + 23068672);     //  8 MB  [1024,4096]
  __bf16* kbuf = (__bf16*)(ws + 31457280);     //  8 MB  [b,i,p,h]
  __bf16* qbuf = (__bf16*)(ws + 39845888);     //  8 MB  [b,i,p,h]
  __bf16* vtb  = (__bf16*)(ws + 48234496);     //  8 MB  [b,i,h,p]
  float*  zb   = (float*)(ws + 56623104);      // 16 MB  [b,p,1024]
  float*  yf   = (float*)(ws + 73400320);      // 16 MB  LN out f32
  __bf16* ybb  = (__bf16*)(ws + 90177536);     //  8 MB  LN out bf16
  __bf16* hact = (__bf16*)(ws + 98566144);     // 32 MB  [4096,4096]

  // fused f32->bf16: 15,728,640 elements / 4 per thread / 256 = 15360 blocks
  k_f2b_all<<<15360, 256, 0, stream>>>(x, W_K, W_Q, W_V, W_in, W_out,
                                       xb, wqkv, winb, woutb);

  // QKV projection: [4096,1024] x [3072,1024]^T  (256x256 tiles, 192 blocks)
  k_gemm<0, 2, 4, 8, 4><<<192, 512, 0, stream>>>(xb, wqkv, 3072, 1024, 12,
                                                 nullptr, nullptr, nullptr,
                                                 nullptr, kbuf, qbuf, vtb);
  // attention: 2048 blocks x 2 waves (split-K), bi->XCD affinity swizzle
  k_attn<<<dim3(2048), 128, 0, stream>>>(kbuf, qbuf, vtb, zb);
  // residual + LN
  k_ln<<<4096, 256, 0, stream>>>(x, zb, w_ln, b_ln, yf, ybb);
  // MLP in + GELU: [4096,1024] x [4096,1024]^T  (256x256 tiles, 256 blocks)
  k_gemm<1, 2, 4, 8, 4><<<256, 512, 0, stream>>>(ybb, winb, 4096, 1024, 16,
                                                 b_in, nullptr, nullptr, hact,
                                                 nullptr, nullptr, nullptr);
  // MLP out + bias + residual: [4096,4096] x [1024,4096]^T (128x128, 256 blocks)
  k_gemm<2, 2, 2, 4, 4><<<256, 256, 0, stream>>>(hact, woutb, 1024, 4096, 8,
                                                 b_out, yf, out, nullptr,
                                                 nullptr, nullptr, nullptr);
}

// Round 12
// 235.860 us; speedup vs baseline: 1.4187x; 1.0515x over previous
//
#include <hip/hip_runtime.h>
#include <hip/hip_bf16.h>

typedef __bf16 bf16x8 __attribute__((ext_vector_type(8)));
typedef float f32x4 __attribute__((ext_vector_type(4)));

#define BAR() __builtin_amdgcn_s_barrier()
#define MEMFENCE() asm volatile("" ::: "memory")
#define VMCNT8() asm volatile("s_waitcnt vmcnt(8)" ::: "memory")
#define VMCNT2() asm volatile("s_waitcnt vmcnt(2)" ::: "memory")
#define VMCNT0() asm volatile("s_waitcnt vmcnt(0)" ::: "memory")

__device__ __forceinline__ void gload_lds16(const void* g, void* l) {
  __builtin_amdgcn_global_load_lds(
      (const __attribute__((address_space(1))) void*)g,
      (__attribute__((address_space(3))) void*)l, 16, 0, 0);
}

// ---------------- fused f32 -> bf16 convert (all 6 tensors) ----------------
// total = 15728640 elements; grid = 15728640/(256*4) = 15360 blocks
__global__ __launch_bounds__(256) void k_f2b_all(
    const float* __restrict__ x, const float* __restrict__ wk,
    const float* __restrict__ wq, const float* __restrict__ wv,
    const float* __restrict__ wi, const float* __restrict__ wo,
    __bf16* __restrict__ xb, __bf16* __restrict__ wqkv,
    __bf16* __restrict__ winb, __bf16* __restrict__ woutb) {
  int i = (blockIdx.x * 256 + threadIdx.x) * 4;
  const float* s; __bf16* d; int off;
  if (i < 4194304)       { s = x;  d = xb;             off = i; }
  else if (i < 5242880)  { s = wk; d = wqkv;           off = i - 4194304; }
  else if (i < 6291456)  { s = wq; d = wqkv + 1048576; off = i - 5242880; }
  else if (i < 7340032)  { s = wv; d = wqkv + 2097152; off = i - 6291456; }
  else if (i < 11534336) { s = wi; d = winb;           off = i - 7340032; }
  else                   { s = wo; d = woutb;          off = i - 11534336; }
  const float4 v = *(const float4*)(s + off);
  d[off + 0] = (__bf16)v.x;
  d[off + 1] = (__bf16)v.y;
  d[off + 2] = (__bf16)v.z;
  d[off + 3] = (__bf16)v.w;
}

// ---------------- NT GEMM v2: counted-vmcnt double-buffered pipeline -------
template <int EPI, int WM, int WN, int MI, int NI>
__global__ __launch_bounds__(WM * WN * 64, 2) void k_gemm(
    const __bf16* __restrict__ A, const __bf16* __restrict__ B, int N, int K,
    int NT, const float* __restrict__ bias, const float* __restrict__ resid,
    float* __restrict__ outf, __bf16* __restrict__ outb,
    __bf16* __restrict__ ok, __bf16* __restrict__ oq, __bf16* __restrict__ ovt) {
  constexpr int BM = WM * MI * 16, BN = WN * NI * 16;
  constexpr int LA = BM / (8 * WM * WN);
  constexpr int LB = BN / (8 * WM * WN);
  __shared__ __align__(16) __bf16 lds[2][(BM + BN) * 64];
  const int tid = threadIdx.x;
  const int lane = tid & 63, wid = tid >> 6;
  const int wr = wid / WN, wc = wid % WN;
  const int lr = lane & 15, lh = lane >> 4;
  const int bid = blockIdx.x;
  const int cpx = gridDim.x >> 3;
  const int sid = (bid & 7) * cpx + (bid >> 3);
  const int mt = sid / NT, nt = sid - mt * NT;
  const int m0 = mt * BM, n0 = nt * BN;
  const int nkt = K >> 6;

  auto stage = [&](int t, int bufi) {
    const int k0 = t << 6;
    __bf16* As = lds[bufi];
    __bf16* Bs = lds[bufi] + BM * 64;
#pragma unroll
    for (int j = 0; j < LA; ++j) {
      int chunk = (wid * LA + j) * 64 + lane;
      int row = chunk >> 3, c8 = chunk & 7;
      int g8 = c8 ^ (row & 7);
      gload_lds16(A + (size_t)(m0 + row) * K + k0 + g8 * 8, As + chunk * 8);
    }
#pragma unroll
    for (int j = 0; j < LB; ++j) {
      int chunk = (wid * LB + j) * 64 + lane;
      int row = chunk >> 3, c8 = chunk & 7;
      int g8 = c8 ^ (row & 7);
      gload_lds16(B + (size_t)(n0 + row) * K + k0 + g8 * 8, Bs + chunk * 8);
    }
  };

  f32x4 acc[MI][NI] = {};
  stage(0, 0);
  stage(1, 1);
  VMCNT8();
  BAR();

  for (int t = 0; t < nkt; ++t) {
    const __bf16* As = lds[t & 1];
    const __bf16* Bs = lds[t & 1] + BM * 64;
#pragma unroll
    for (int ks = 0; ks < 2; ++ks) {
      bf16x8 af[MI], bf[NI];
#pragma unroll
      for (int mi = 0; mi < MI; ++mi) {
        int row = wr * (MI * 16) + mi * 16 + lr;
        af[mi] = *(const bf16x8*)&As[row * 64 + (((ks * 4 + lh) ^ (row & 7)) * 8)];
      }
#pragma unroll
      for (int ni = 0; ni < NI; ++ni) {
        int row = wc * (NI * 16) + ni * 16 + lr;
        bf[ni] = *(const bf16x8*)&Bs[row * 64 + (((ks * 4 + lh) ^ (row & 7)) * 8)];
      }
#pragma unroll
      for (int mi = 0; mi < MI; ++mi)
#pragma unroll
        for (int ni = 0; ni < NI; ++ni)
          acc[mi][ni] = __builtin_amdgcn_mfma_f32_16x16x32_bf16(
              af[mi], bf[ni], acc[mi][ni], 0, 0, 0);
    }
    MEMFENCE();
    BAR();
    if (t + 2 < nkt) {
      stage(t + 2, t & 1);
      VMCNT8();
    } else {
      VMCNT0();
    }
    BAR();
  }

#pragma unroll
  for (int mi = 0; mi < MI; ++mi) {
#pragma unroll
    for (int j = 0; j < 4; ++j) {
      const int row = m0 + wr * (MI * 16) + mi * 16 + lh * 4 + j;
#pragma unroll
      for (int ni = 0; ni < NI; ++ni) {
        const int col = n0 + wc * (NI * 16) + ni * 16 + lr;
        float v = acc[mi][ni][j];
        if constexpr (EPI == 0) {
          const int which = col >> 10, c = col & 1023;
          const int ih = c >> 6, hh = c & 63;
          const int bb = row >> 11, pp = row & 2047;
          const int bi = bb * 16 + ih;
          if (which == 0)
            ok[((size_t)bi * 2048 + pp) * 64 + hh] = (__bf16)v;
          else if (which == 1)
            oq[((size_t)bi * 2048 + pp) * 64 + hh] = (__bf16)v;
          else
            ovt[((size_t)bi * 64 + hh) * 2048 + pp] = (__bf16)v;
        } else if constexpr (EPI == 1) {
          float h = v + bias[col];
          float g = 0.5f * h * (1.f + erff(h * 0.70710678118f));
          outb[(size_t)row * N + col] = (__bf16)g;
        } else {
          outf[(size_t)row * N + col] = v + bias[col] + resid[(size_t)row * N + col];
        }
      }
    }
  }
}

// ---------------- flash attention v7: 8-wave LDS-staged block ---------------
// Structure = the proven k_gemm pipeline applied to attention:
// 1 block = 512 threads = 8 waves, one (bi, 256-q-row) tile; K/V kv-step tiles
// (64x64 each) staged ONCE into double-buffered LDS via global_load_lds
// (counted VMCNT2 = per-thread loads/tile, raw barriers, both-sides XOR
// swizzle) and shared by all 8 waves -> 8x fewer global loads than v6.
// Wave w owns q-rows [qw, qw+31]; causal gating is wave-uniform; no combine.
// No max tracking (|s|<~55 -> exp(s) safely inside f32; softmax is a ratio).
__global__ __launch_bounds__(512) void k_attn(const __bf16* __restrict__ kb,
                                              const __bf16* __restrict__ qb,
                                              const __bf16* __restrict__ vt,
                                              float* __restrict__ z) {
  const int tid = threadIdx.x;
  const int lane = tid & 63, w = tid >> 6;
  const int lr = lane & 15, lh = lane >> 4;
  const int wgid = blockIdx.x;        // 256 blocks = 1/CU
  const int xcd = wgid & 7;
  const int t = wgid >> 3;            // 0..31
  const int bi = xcd + 8 * (t & 3);   // bi % 8 == xcd
  const int qblk = t >> 2;            // 0..7
  const int b = bi >> 4, ih = bi & 15;
  const int q0B = qblk * 256;
  const int qw = q0B + w * 32;        // this wave's q base
  const __bf16* kbase = kb + (size_t)bi * 2048 * 64;
  const __bf16* qbase = qb + (size_t)bi * 2048 * 64;
  const __bf16* vbase = vt + (size_t)bi * 64 * 2048;

  // LDS: double-buffered K and V tiles (64 rows x 64 cols, XOR-swizzled)
  __shared__ __align__(16) __bf16 kv[2][2][64 * 64];  // [buf][K=0/V=1] 32 KB
  __shared__ __align__(16) __bf16 plds[8][2][16 * 76]; // wave-private P, 38 KB

  const int nk = (q0B >> 6) + 4;  // ceil((q0B+256)/64)

  // stage kv-tile kt into buffer bufi: 2 gload_lds16 per thread (K then V)
  auto stage = [&](int kt, int bufi) {
    const int k0 = kt << 6;
    const int row = tid >> 3, c8 = tid & 7;
    const int g8 = c8 ^ (row & 7);  // inverse swizzle on global source
    gload_lds16(kbase + (size_t)(k0 + row) * 64 + g8 * 8,
                &kv[bufi][0][tid * 8]);
    gload_lds16(vbase + (size_t)row * 2048 + k0 + g8 * 8,
                &kv[bufi][1][tid * 8]);
  };

  // Q fragments for this wave's 32 rows
  bf16x8 aq[2][2];
#pragma unroll
  for (int tl = 0; tl < 2; ++tl)
#pragma unroll
    for (int ks = 0; ks < 2; ++ks)
      aq[tl][ks] = *(const bf16x8*)(qbase + (size_t)(qw + tl * 16 + lr) * 64 + ks * 32 + lh * 8);

  f32x4 o[2][4] = {};
  float lsum[2][4] = {};

  stage(0, 0);
  stage(1, 1);
  VMCNT2();  // tile 0 landed (tile 1's 2 loads still in flight)
  BAR();

  for (int kt = 0; kt < nk; ++kt) {
    const int k0 = kt << 6;
    const __bf16* Ks = kv[kt & 1][0];
    const __bf16* Vs = kv[kt & 1][1];
    const bool act = (k0 <= qw + 31);  // wave-uniform causal gate

    if (act) {
      // K fragments from LDS (swizzled) + QK^T
      bf16x8 bk[4][2];
#pragma unroll
      for (int n = 0; n < 4; ++n) {
        int r = n * 16 + lr;
#pragma unroll
        for (int ks = 0; ks < 2; ++ks)
          bk[n][ks] = *(const bf16x8*)&Ks[r * 64 + (((ks * 4 + lh) ^ (r & 7)) * 8)];
      }
      f32x4 s[2][4] = {};
#pragma unroll
      for (int ks = 0; ks < 2; ++ks)
#pragma unroll
        for (int n = 0; n < 4; ++n) {
          s[0][n] = __builtin_amdgcn_mfma_f32_16x16x32_bf16(aq[0][ks], bk[n][ks], s[0][n], 0, 0, 0);
          s[1][n] = __builtin_amdgcn_mfma_f32_16x16x32_bf16(aq[1][ks], bk[n][ks], s[1][n], 0, 0, 0);
        }

      // V fragments (issued before softmax so lgkm latency overlaps VALU)
      bf16x8 bv[4][2];
#pragma unroll
      for (int ht = 0; ht < 4; ++ht) {
        int r = ht * 16 + lr;
#pragma unroll
        for (int ks = 0; ks < 2; ++ks)
          bv[ht][ks] = *(const bf16x8*)&Vs[r * 64 + (((ks * 4 + lh) ^ (r & 7)) * 8)];
      }

      if (k0 + 63 > qw) {  // tile straddles this wave's diagonal
#pragma unroll
        for (int tl = 0; tl < 2; ++tl)
#pragma unroll
          for (int n = 0; n < 4; ++n)
#pragma unroll
            for (int j = 0; j < 4; ++j) {
              int qpos = qw + tl * 16 + lh * 4 + j;
              int kpos = k0 + n * 16 + lr;
              if (kpos > qpos) s[tl][n][j] = -1e10f;
            }
      }

      // exp in place + partial row sums
#pragma unroll
      for (int tl = 0; tl < 2; ++tl) {
#pragma unroll
        for (int n = 0; n < 4; ++n)
#pragma unroll
          for (int j = 0; j < 4; ++j) s[tl][n][j] = __expf(s[tl][n][j]);
#pragma unroll
        for (int j = 0; j < 4; ++j)
          lsum[tl][j] += (s[tl][0][j] + s[tl][1][j]) + (s[tl][2][j] + s[tl][3][j]);
      }

      // P transpose through wave-private LDS (intra-wave lgkmcnt ordering)
#pragma unroll
      for (int tl = 0; tl < 2; ++tl)
#pragma unroll
        for (int n = 0; n < 4; ++n)
#pragma unroll
          for (int j = 0; j < 4; ++j)
            plds[w][tl][(lh * 4 + j) * 76 + n * 16 + lr] = (__bf16)s[tl][n][j];
      bf16x8 pa[2][2];
#pragma unroll
      for (int tl = 0; tl < 2; ++tl)
#pragma unroll
        for (int ks = 0; ks < 2; ++ks)
          pa[tl][ks] = *(const bf16x8*)&plds[w][tl][lr * 76 + ks * 32 + lh * 8];
#pragma unroll
      for (int ks = 0; ks < 2; ++ks)
#pragma unroll
        for (int ht = 0; ht < 4; ++ht) {
          o[0][ht] = __builtin_amdgcn_mfma_f32_16x16x32_bf16(pa[0][ks], bv[ht][ks], o[0][ht], 0, 0, 0);
          o[1][ht] = __builtin_amdgcn_mfma_f32_16x16x32_bf16(pa[1][ks], bv[ht][ks], o[1][ht], 0, 0, 0);
        }
    }

    MEMFENCE();
    BAR();  // all waves done reading buf[kt&1]
    if (kt + 2 < nk) {
      stage(kt + 2, kt & 1);
      VMCNT2();  // tile kt+1's loads (all waves') done; kt+2's stay in flight
    } else {
      VMCNT0();
    }
    BAR();  // buf[(kt+1)&1] ready for all waves
  }

  // row sum over the 16 lr lanes
#pragma unroll
  for (int m = 1; m < 16; m <<= 1)
#pragma unroll
    for (int tl = 0; tl < 2; ++tl)
#pragma unroll
      for (int j = 0; j < 4; ++j) lsum[tl][j] += __shfl_xor(lsum[tl][j], m);

  float* zr = z + (size_t)b * 2048 * 1024;
#pragma unroll
  for (int tl = 0; tl < 2; ++tl)
#pragma unroll
    for (int j = 0; j < 4; ++j) {
      float inv = 1.f / lsum[tl][j];
      int q = qw + tl * 16 + lh * 4 + j;
#pragma unroll
      for (int ht = 0; ht < 4; ++ht)
        zr[(size_t)q * 1024 + ih * 64 + ht * 16 + lr] = o[tl][ht][j] * inv;
    }
}

// ---------------- residual + custom LayerNorm ----------------
__global__ __launch_bounds__(256) void k_ln(const float* __restrict__ x,
                                            const float* __restrict__ z,
                                            const float* __restrict__ wln,
                                            const float* __restrict__ bln,
                                            float* __restrict__ y,
                                            __bf16* __restrict__ yb) {
  const int row = blockIdx.x;
  const int t = threadIdx.x;
  const int lane = t & 63, wid = t >> 6;
  const float4 xv = ((const float4*)(x + (size_t)row * 1024))[t];
  const float4 zv = ((const float4*)(z + (size_t)row * 1024))[t];
  float v0 = xv.x + zv.x, v1 = xv.y + zv.y, v2 = xv.z + zv.z, v3 = xv.w + zv.w;
  __shared__ float red[4];
  float s = v0 + v1 + v2 + v3;
#pragma unroll
  for (int m = 1; m < 64; m <<= 1) s += __shfl_xor(s, m);
  if (lane == 0) red[wid] = s;
  __syncthreads();
  const float mean = (red[0] + red[1] + red[2] + red[3]) * (1.f / 1024.f);
  const float c0 = v0 - mean, c1 = v1 - mean, c2 = v2 - mean, c3 = v3 - mean;
  float ss = c0 * c0 + c1 * c1 + c2 * c2 + c3 * c3;
#pragma unroll
  for (int m = 1; m < 64; m <<= 1) ss += __shfl_xor(ss, m);
  __syncthreads();
  if (lane == 0) red[wid] = ss;
  __syncthreads();
  const float var = (red[0] + red[1] + red[2] + red[3]) * (1.f / 1023.f);
  const float inv = 1.f / (sqrtf(var) + 1e-4f);
  const float4 wv = ((const float4*)wln)[t];
  const float4 bv = ((const float4*)bln)[t];
  float y0 = c0 * inv * wv.x + bv.x;
  float y1 = c1 * inv * wv.y + bv.y;
  float y2 = c2 * inv * wv.z + bv.z;
  float y3 = c3 * inv * wv.w + bv.w;
  float4 yo; yo.x = y0; yo.y = y1; yo.z = y2; yo.w = y3;
  ((float4*)(y + (size_t)row * 1024))[t] = yo;
  __bf16* yd = yb + (size_t)row * 1024 + t * 4;
  yd[0] = (__bf16)y0; yd[1] = (__bf16)y1; yd[2] = (__bf16)y2; yd[3] = (__bf16)y3;
}

// ---------------- launch ----------------
extern "C" void kernel_launch(void* const* d_in, const int* in_sizes, int n_in,
                              void* d_out, int out_size, void* d_ws, size_t ws_size,
                              hipStream_t stream) {
  const float* x = (const float*)d_in[0];
  const float* W_K = (const float*)d_in[1];
  const float* W_Q = (const float*)d_in[2];
  const float* W_V = (const float*)d_in[3];
  const float* w_ln = (const float*)d_in[4];
  const float* b_ln = (const float*)d_in[5];
  const float* W_in = (const float*)d_in[6];
  const float* b_in = (const float*)d_in[7];
  const float* W_out = (const float*)d_in[8];
  const float* b_out = (const float*)d_in[9];
  float* out = (float*)d_out;

  char* ws = (char*)d_ws;
  const size_t NEEDED = 132120576;  // ~126 MB
  if (ws_size < NEEDED) return;

  __bf16* xb   = (__bf16*)(ws);                //  8 MB  [4096,1024]
  __bf16* wqkv = (__bf16*)(ws + 8388608);      //  6 MB  [3072,1024] K,Q,V stacked
  __bf16* winb = (__bf16*)(ws + 14680064);     //  8 MB  [4096,1024]
  __bf16* woutb= (__bf16*)(ws + 23068672);     //  8 MB  [1024,4096]
  __bf16* kbuf = (__bf16*)(ws + 31457280);     //  8 MB  [b,i,p,h]
  __bf16* qbuf = (__bf16*)(ws + 39845888);     //  8 MB  [b,i,p,h]
  __bf16* vtb  = (__bf16*)(ws + 48234496);     //  8 MB  [b,i,h,p]
  float*  zb   = (float*)(ws + 56623104);      // 16 MB  [b,p,1024]
  float*  yf   = (float*)(ws + 73400320);      // 16 MB  LN out f32
  __bf16* ybb  = (__bf16*)(ws + 90177536);     //  8 MB  LN out bf16
  __bf16* hact = (__bf16*)(ws + 98566144);     // 32 MB  [4096,4096]

  // fused f32->bf16: 15,728,640 elements / 4 per thread / 256 = 15360 blocks
  k_f2b_all<<<15360, 256, 0, stream>>>(x, W_K, W_Q, W_V, W_in, W_out,
                                       xb, wqkv, winb, woutb);

  // QKV projection: [4096,1024] x [3072,1024]^T  (256x256 tiles, 192 blocks)
  k_gemm<0, 2, 4, 8, 4><<<192, 512, 0, stream>>>(xb, wqkv, 3072, 1024, 12,
                                                 nullptr, nullptr, nullptr,
                                                 nullptr, kbuf, qbuf, vtb);
  // attention: 256 blocks x 8 waves, LDS-staged K/V, bi->XCD affinity
  k_attn<<<dim3(256), 512, 0, stream>>>(kbuf, qbuf, vtb, zb);
  // residual + LN
  k_ln<<<4096, 256, 0, stream>>>(x, zb, w_ln, b_ln, yf, ybb);
  // MLP in + GELU: [4096,1024] x [4096,1024]^T  (256x256 tiles, 256 blocks)
  k_gemm<1, 2, 4, 8, 4><<<256, 512, 0, stream>>>(ybb, winb, 4096, 1024, 16,
                                                 b_in, nullptr, nullptr, hact,
                                                 nullptr, nullptr, nullptr);
  // MLP out + bias + residual: [4096,4096] x [1024,4096]^T (128x128, 256 blocks)
  k_gemm<2, 2, 2, 4, 4><<<256, 256, 0, stream>>>(hact, woutb, 1024, 4096, 8,
                                                 b_out, yf, out, nullptr,
                                                 nullptr, nullptr, nullptr);
}